// Round 6
// baseline (1064.382 us; speedup 1.0000x reference)
//
#include <hip/hip_runtime.h>
#include <math.h>

#define Hh 256
#define Ww 256
#define HW 65536
#define Bn 4
#define Cdim 60
#define Ce 120
#define NPIX (Bn*HW)

typedef const float* fp;

__device__ __forceinline__ float gelu_exact(float x){
  return 0.5f*x*(1.f + erff(x*0.70710678118654752f));
}

// decode 64-px tile id -> (b, h, tw). 1024 tiles/image (256 rows x 4 tiles).
__device__ __forceinline__ void tile_decode(int blk, int& b, int& h, int& tw){
  b = blk >> 10; int rem = blk & 1023; h = rem >> 2; tw = (rem & 3) << 6;
}

// ---------------- LFE stage 1: y1 = gelu(conv1x1(shift(src), w0, b0)) ----------------
// GEMM: M=64 px, N=120 out, K=60. W staged TRANSPOSED [k][o] stride 132 so the
// 8 per-k W broadcasts become 2 conflict-free ds_read_b128.
__global__ __launch_bounds__(256) void k_lfe1(const float* __restrict__ X, float* __restrict__ Y1,
                                              fp w0, fp b0){
  __shared__ __align__(16) float A[60*64];     // shifted input [k][p]
  __shared__ __align__(16) float Wt[60*132];   // transposed weights [k][o], stride 132
  int tid = threadIdx.x;
  int b, h, tw; tile_decode(blockIdx.x, b, h, tw);
  const float* Xb = X + (size_t)b*(Cdim*HW);
  for (int idx = tid; idx < 60*64; idx += 256){
    int k = idx >> 6, p = idx & 63;
    int grp = k / 12;
    int hh = h, ww = tw + p; bool ok = true;
    if (grp == 0){ ww += 1; ok = (ww < Ww); }
    else if (grp == 1){ ww -= 1; ok = (ww >= 0); }
    else if (grp == 2){ hh = h+1; ok = (hh < Hh); }
    else if (grp == 3){ hh = h-1; ok = (hh >= 0); }
    A[idx] = ok ? Xb[k*HW + hh*Ww + ww] : 0.f;
  }
  for (int idx = tid; idx < 120*60; idx += 256){   // coalesced read; transposed write
    int o = idx / 60, k = idx - o*60;
    Wt[k*132 + o] = w0[idx];
  }
  __syncthreads();
  if (tid < 240){
    int p0 = (tid & 15)*4;
    int o0 = (tid >> 4)*8;
    float acc[8][4];
    #pragma unroll
    for (int oi = 0; oi < 8; oi++){
      float bb = b0[o0+oi];
      #pragma unroll
      for (int pi = 0; pi < 4; pi++) acc[oi][pi] = bb;
    }
    #pragma unroll 4
    for (int k = 0; k < 60; k++){
      float4 a4 = *(const float4*)(&A[k*64 + p0]);
      float av[4] = {a4.x,a4.y,a4.z,a4.w};
      float4 wa = *(const float4*)(&Wt[k*132 + o0]);
      float4 wb = *(const float4*)(&Wt[k*132 + o0 + 4]);
      float wv[8] = {wa.x,wa.y,wa.z,wa.w, wb.x,wb.y,wb.z,wb.w};
      #pragma unroll
      for (int oi = 0; oi < 8; oi++){
        #pragma unroll
        for (int pi = 0; pi < 4; pi++)
          acc[oi][pi] += wv[oi]*av[pi];
      }
    }
    float* Yb = Y1 + (size_t)b*(Ce*HW) + h*Ww + tw + p0;
    #pragma unroll
    for (int oi = 0; oi < 8; oi++){
      float4 r;
      r.x = gelu_exact(acc[oi][0]); r.y = gelu_exact(acc[oi][1]);
      r.z = gelu_exact(acc[oi][2]); r.w = gelu_exact(acc[oi][3]);
      *(float4*)(Yb + (size_t)(o0+oi)*HW) = r;
    }
  }
}

// ---------------- LFE stage 2: X = conv1x1(shift(y1), w1, b1) + resid ----------------
// GEMM: M=64, N=60, K=120 (A staged in two 60-row halves). W transposed [e][c] stride 68.
__global__ __launch_bounds__(256) void k_lfe2(const float* __restrict__ Y1,
                                              const float* __restrict__ R,
                                              float* __restrict__ X,
                                              fp w1, fp b1){
  __shared__ __align__(16) float A[60*64];
  __shared__ __align__(16) float Wt[120*68];   // transposed [e][c], stride 68
  int tid = threadIdx.x;
  int b, h, tw; tile_decode(blockIdx.x, b, h, tw);
  const float* Yb = Y1 + (size_t)b*(Ce*HW);
  for (int idx = tid; idx < 60*120; idx += 256){
    int c = idx / 120, e = idx - c*120;
    Wt[e*68 + c] = w1[idx];
  }
  int p0 = (tid & 15)*4;
  int o0 = (tid >> 4)*4;
  float acc[4][4];
  #pragma unroll
  for (int oi = 0; oi < 4; oi++)
    #pragma unroll
    for (int pi = 0; pi < 4; pi++) acc[oi][pi] = 0.f;
  #pragma unroll 1
  for (int half = 0; half < 2; half++){
    __syncthreads();                            // W ready / previous half's GEMM reads done
    for (int idx = tid; idx < 60*64; idx += 256){
      int k = idx >> 6, p = idx & 63;
      int e = half*60 + k;
      int grp = e / 24;
      int hh = h, ww = tw + p; bool ok = true;
      if (grp == 0){ ww += 1; ok = (ww < Ww); }
      else if (grp == 1){ ww -= 1; ok = (ww >= 0); }
      else if (grp == 2){ hh = h+1; ok = (hh < Hh); }
      else if (grp == 3){ hh = h-1; ok = (hh >= 0); }
      A[idx] = ok ? Yb[e*HW + hh*Ww + ww] : 0.f;
    }
    __syncthreads();
    if (tid < 240){
      #pragma unroll 4
      for (int k = 0; k < 60; k++){
        float4 a4 = *(const float4*)(&A[k*64 + p0]);
        float av[4] = {a4.x,a4.y,a4.z,a4.w};
        float4 w4 = *(const float4*)(&Wt[(half*60 + k)*68 + o0]);
        float wv[4] = {w4.x,w4.y,w4.z,w4.w};
        #pragma unroll
        for (int oi = 0; oi < 4; oi++){
          #pragma unroll
          for (int pi = 0; pi < 4; pi++)
            acc[oi][pi] += wv[oi]*av[pi];
        }
      }
    }
  }
  if (tid < 240){
    const float* Rp = R + (size_t)b*(Cdim*HW) + h*Ww + tw + p0;
    float* Xp = X + (size_t)b*(Cdim*HW) + h*Ww + tw + p0;
    #pragma unroll
    for (int oi = 0; oi < 4; oi++){
      int o = o0 + oi;
      float bb = b1[o];
      float4 r4 = *(const float4*)(Rp + (size_t)o*HW);
      float4 out;
      out.x = acc[oi][0] + bb + r4.x;
      out.y = acc[oi][1] + bb + r4.y;
      out.z = acc[oi][2] + bb + r4.z;
      out.w = acc[oi][3] + bb + r4.w;
      *(float4*)(Xp + (size_t)o*HW) = out;
    }
  }
}

// ---------------- WSA stage 1: t = BN(conv1x1(x, pi_w, pi_b)) ----------------
// GEMM: M=64, N=60, K=60. W transposed [k][o] stride 68 with BN scale folded at staging.
__global__ __launch_bounds__(256) void k_wsat(const float* __restrict__ X, float* __restrict__ T,
                                              fp piw, fp pib, fp g, fp bt, fp m, fp v){
  __shared__ __align__(16) float A[60*64];
  __shared__ __align__(16) float Wt[60*68];
  int tid = threadIdx.x;
  int b, h, tw; tile_decode(blockIdx.x, b, h, tw);
  const float* Xb = X + (size_t)b*(Cdim*HW) + h*Ww + tw;
  for (int idx = tid; idx < 60*64; idx += 256){
    int k = idx >> 6, p = idx & 63;
    A[idx] = Xb[k*HW + p];
  }
  for (int idx = tid; idx < 60*60; idx += 256){
    int o = idx / 60, k = idx - o*60;
    float scale = g[o] * rsqrtf(v[o] + 1e-5f);
    Wt[k*68 + o] = piw[idx] * scale;
  }
  __syncthreads();
  if (tid < 240){
    int p0 = (tid & 15)*4;
    int o0 = (tid >> 4)*4;
    float acc[4][4];
    #pragma unroll
    for (int oi = 0; oi < 4; oi++)
      #pragma unroll
      for (int pi = 0; pi < 4; pi++) acc[oi][pi] = 0.f;
    #pragma unroll 4
    for (int k = 0; k < 60; k++){
      float4 a4 = *(const float4*)(&A[k*64 + p0]);
      float av[4] = {a4.x,a4.y,a4.z,a4.w};
      float4 w4 = *(const float4*)(&Wt[k*68 + o0]);
      float wv[4] = {w4.x,w4.y,w4.z,w4.w};
      #pragma unroll
      for (int oi = 0; oi < 4; oi++){
        #pragma unroll
        for (int pi = 0; pi < 4; pi++)
          acc[oi][pi] += wv[oi]*av[pi];
      }
    }
    float* Tb = T + (size_t)b*(Cdim*HW) + h*Ww + tw + p0;
    #pragma unroll
    for (int oi = 0; oi < 4; oi++){
      int o = o0 + oi;
      float scale = g[o] * rsqrtf(v[o] + 1e-5f);
      float cns   = (pib[o] - m[o])*scale + bt[o];
      float4 out;
      out.x = acc[oi][0] + cns;
      out.y = acc[oi][1] + cns;
      out.z = acc[oi][2] + cns;
      out.w = acc[oi][3] + cns;
      *(float4*)(Tb + (size_t)o*HW) = out;
    }
  }
}

// ---------------- WSA stage 2+3 FUSED: windowed attention + po conv + resid ----------------
// After PV, y (60ch x 64px) lives in-block: write y into R2 (S dead), stage po_w^T
// into R1 (V dead), run the po GEMM as an epilogue and RMW X directly.
__global__ __launch_bounds__(256) void k_attn(const float* __restrict__ T, float* __restrict__ X,
                                              fp mw, fp mb, fp pw, fp pb){
  __shared__ __align__(16) float R1[64*68]; // sub[k*68+p] -> V[tok*68+c] -> poW^T[k*68+o]
  __shared__ __align__(16) float R2[64*68]; // Wn[c*61+k] -> St[q*68+p] -> y[c*68+p]
  __shared__ __align__(16) float R3[60*64]; // Qt[c*64+tok] -> softmax partials scratch
  int tid = threadIdx.x;
  int blk = blockIdx.x;
  int b = blk >> 10; int ij = blk & 1023; int wi = ij >> 5; int wj = ij & 31;
  const float* Tb = T + (size_t)b*(Cdim*HW);

  for (int idx = tid; idx < Cdim*64; idx += 256){
    int k = idx >> 6, p = idx & 63;
    int u = p >> 3, vq = p & 7;
    int r  = wi*8 + 2*vq; if (r > 255) r -= 8;
    int cc = wj*8 + 2*u;  if (cc > 255) cc -= 8;
    R1[k*68 + p] = Tb[k*HW + r*Ww + cc];
  }
  for (int idx = tid; idx < Cdim*Cdim; idx += 256){   // coalesced, natural layout
    int c = idx / Cdim, k = idx - c*Cdim;
    R2[c*61 + k] = mw[idx];
  }
  __syncthreads();

  // qproj: q[p][c] = sum_k mw[c][k]*sub[k][p] + mb[c]
  if (tid < 240){
    int p0 = (tid & 15)*4, c0 = (tid >> 4)*4;
    float4 mb4 = *(const float4*)(mb + c0);
    float bias[4] = {mb4.x, mb4.y, mb4.z, mb4.w};
    float acc[4][4];
    #pragma unroll
    for (int ci = 0; ci < 4; ci++)
      #pragma unroll
      for (int pi = 0; pi < 4; pi++) acc[ci][pi] = bias[ci];
    #pragma unroll 4
    for (int k = 0; k < Cdim; k++){
      float4 a4 = *(const float4*)(&R1[k*68 + p0]);
      float av[4] = {a4.x, a4.y, a4.z, a4.w};
      #pragma unroll
      for (int ci = 0; ci < 4; ci++){
        float wv = R2[(c0+ci)*61 + k];
        #pragma unroll
        for (int pi = 0; pi < 4; pi++)
          acc[ci][pi] += wv*av[pi];
      }
    }
    #pragma unroll
    for (int ci = 0; ci < 4; ci++)
      *(float4*)(&R3[(c0+ci)*64 + p0]) = make_float4(acc[ci][0], acc[ci][1], acc[ci][2], acc[ci][3]);
  }
  __syncthreads();

  // stage V[tok][c] into R1 (sub dead); compute scores from R3
  {
    int p = tid & 63; int cg = tid >> 6;
    int pr = p >> 3, pc = p & 7;
    const float* base = Tb + (wi*8+pr)*Ww + (wj*8+pc);
    #pragma unroll
    for (int t2 = 0; t2 < 15; t2++)
      R1[p*68 + cg*15 + t2] = base[(cg*15+t2)*HW];
  }
  if (tid < 64){
    R1[tid*68 + 60] = 0.f; R1[tid*68 + 61] = 0.f;
    R1[tid*68 + 62] = 0.f; R1[tid*68 + 63] = 0.f;
  }
  {
    int p0 = (tid & 15)*4, q0 = (tid >> 4)*4;
    float acc[4][4];
    #pragma unroll
    for (int qi = 0; qi < 4; qi++)
      #pragma unroll
      for (int pi = 0; pi < 4; pi++) acc[qi][pi] = 0.f;
    #pragma unroll 4
    for (int c = 0; c < Cdim; c++){
      float4 A4 = *(const float4*)(&R3[c*64 + p0]);
      float4 B4 = *(const float4*)(&R3[c*64 + q0]);
      float Af[4] = {A4.x, A4.y, A4.z, A4.w};
      float Bf[4] = {B4.x, B4.y, B4.z, B4.w};
      #pragma unroll
      for (int qi = 0; qi < 4; qi++)
        #pragma unroll
        for (int pi = 0; pi < 4; pi++)
          acc[qi][pi] += Bf[qi]*Af[pi];
    }
    __syncthreads();   // qproj reads of R2/R3 done; V-stage R1 writes done
    #pragma unroll
    for (int qi = 0; qi < 4; qi++)
      *(float4*)(&R2[(q0+qi)*68 + p0]) = make_float4(acc[qi][0], acc[qi][1], acc[qi][2], acc[qi][3]);
  }
  __syncthreads();

  // parallel column softmax over q (all 256 threads): thread (gq,p) owns 16 q's.
  {
    int p = tid & 63, gq = tid >> 6;
    float* Sc = R3;                       // Qt dead: [0..255] max partials, [256..511] sums
    float mx = -1e30f;
    #pragma unroll
    for (int i = 0; i < 16; i++) mx = fmaxf(mx, R2[(gq*16+i)*68 + p]);
    Sc[gq*64 + p] = mx;
    __syncthreads();
    float m0 = fmaxf(fmaxf(Sc[p], Sc[64+p]), fmaxf(Sc[128+p], Sc[192+p]));
    float sum = 0.f;
    #pragma unroll
    for (int i = 0; i < 16; i++){
      int q = gq*16 + i;
      float e = __expf(R2[q*68 + p] - m0);
      R2[q*68 + p] = e; sum += e;
    }
    Sc[256 + gq*64 + p] = sum;
    __syncthreads();
    float tot = (Sc[256+p] + Sc[320+p]) + (Sc[384+p] + Sc[448+p]);
    float inv = 1.f/tot;
    #pragma unroll
    for (int i = 0; i < 16; i++) R2[(gq*16+i)*68 + p] *= inv;
  }
  __syncthreads();

  // PV: y[c][p] = sum_q S[q][p] * V[q][c]; then park y in R2 (S dead after barrier)
  {
    int p0 = (tid & 15)*4, c0 = (tid >> 4)*4;
    float acc[4][4];
    #pragma unroll
    for (int ci = 0; ci < 4; ci++)
      #pragma unroll
      for (int pi = 0; pi < 4; pi++) acc[ci][pi] = 0.f;
    #pragma unroll 4
    for (int q = 0; q < 64; q++){
      float4 S4 = *(const float4*)(&R2[q*68 + p0]);
      float4 V4 = *(const float4*)(&R1[q*68 + c0]);
      float Sf[4] = {S4.x, S4.y, S4.z, S4.w};
      float Vf[4] = {V4.x, V4.y, V4.z, V4.w};
      #pragma unroll
      for (int ci = 0; ci < 4; ci++)
        #pragma unroll
        for (int pi = 0; pi < 4; pi++)
          acc[ci][pi] += Sf[pi]*Vf[ci];
    }
    __syncthreads();   // every thread's PV reads of R1 (V) and R2 (S) complete
    if (c0 < Cdim){
      #pragma unroll
      for (int ci = 0; ci < 4; ci++)
        *(float4*)(&R2[(c0+ci)*68 + p0]) = make_float4(acc[ci][0], acc[ci][1], acc[ci][2], acc[ci][3]);
    }
  }
  // stage po_w transposed [k][o] stride 68 into R1 (V dead); coalesced global read
  for (int idx = tid; idx < Cdim*Cdim; idx += 256){
    int o = idx / Cdim, k = idx - o*Cdim;
    R1[k*68 + o] = pw[idx];
  }
  __syncthreads();

  // epilogue GEMM: X[o][pix] += sum_k pw[o][k]*y[k][pix] + pb[o]
  if (tid < 240){
    int p0 = (tid & 15)*4, o0 = (tid >> 4)*4;
    float acc2[4][4];
    #pragma unroll
    for (int oi = 0; oi < 4; oi++)
      #pragma unroll
      for (int pi = 0; pi < 4; pi++) acc2[oi][pi] = 0.f;
    #pragma unroll 4
    for (int k = 0; k < Cdim; k++){
      float4 y4 = *(const float4*)(&R2[k*68 + p0]);
      float4 w4 = *(const float4*)(&R1[k*68 + o0]);
      float yv[4] = {y4.x,y4.y,y4.z,y4.w};
      float wv[4] = {w4.x,w4.y,w4.z,w4.w};
      #pragma unroll
      for (int oi = 0; oi < 4; oi++){
        #pragma unroll
        for (int pi = 0; pi < 4; pi++)
          acc2[oi][pi] += wv[oi]*yv[pi];
      }
    }
    int prow = wi*8 + (p0 >> 3), pcol = wj*8 + (p0 & 7);
    float* Xp = X + (size_t)b*(Cdim*HW) + prow*Ww + pcol;
    #pragma unroll
    for (int oi = 0; oi < 4; oi++){
      int o = o0 + oi;
      float bb = pb[o];
      float4 r4 = *(const float4*)(Xp + (size_t)o*HW);
      float4 out;
      out.x = acc2[oi][0] + bb + r4.x;
      out.y = acc2[oi][1] + bb + r4.y;
      out.z = acc2[oi][2] + bb + r4.z;
      out.w = acc2[oi][3] + bb + r4.w;
      *(float4*)(Xp + (size_t)o*HW) = out;
    }
  }
}

extern "C" void kernel_launch(void* const* d_in, const int* in_sizes, int n_in,
                              void* d_out, int out_size, void* d_ws, size_t ws_size,
                              hipStream_t stream){
  fp x      = (fp)d_in[0];
  fp lfe_w0 = (fp)d_in[1];
  fp lfe_b0 = (fp)d_in[2];
  fp lfe_w1 = (fp)d_in[3];
  fp lfe_b1 = (fp)d_in[4];
  fp pi_w   = (fp)d_in[5];
  fp pi_b   = (fp)d_in[6];
  fp bn_g   = (fp)d_in[7];
  fp bn_b   = (fp)d_in[8];
  fp bn_m   = (fp)d_in[9];
  fp bn_v   = (fp)d_in[10];
  fp mask_w = (fp)d_in[11];
  fp mask_b = (fp)d_in[12];
  fp po_w   = (fp)d_in[13];
  fp po_b   = (fp)d_in[14];

  const size_t XSZ = (size_t)Bn*Cdim*HW;     // 15,728,640 floats (63 MB)
  float* X  = (float*)d_out;                 // residual stream lives in d_out (fp32)
  float* Y1 = (float*)d_ws;                  // [0, 2*XSZ): 120-ch LFE intermediate
  float* T  = Y1;                            // [0, XSZ): t-tensor (Y1 dead by then)

  const int NT = NPIX/64;                    // 4096 64-px tiles

  for (int d = 0; d < 2; d++){
    fp src = (d == 0) ? x : X;               // depth-0 reads the input directly
    k_lfe1  <<<NT, 256, 0, stream>>>(src, Y1, lfe_w0 + d*Ce*Cdim, lfe_b0 + d*Ce);
    k_lfe2  <<<NT, 256, 0, stream>>>(Y1, src, X, lfe_w1 + d*Ce*Cdim, lfe_b1 + d*Cdim);
    k_wsat  <<<NT, 256, 0, stream>>>(X, T, pi_w + d*Cdim*Cdim, pi_b + d*Cdim,
                                     bn_g + d*Cdim, bn_b + d*Cdim, bn_m + d*Cdim, bn_v + d*Cdim);
    k_attn  <<<Bn*32*32, 256, 0, stream>>>(T, X, mask_w + d*Cdim*Cdim, mask_b + d*Cdim,
                                           po_w + d*Cdim*Cdim, po_b + d*Cdim);
  }
}

// Round 7
// 1020.568 us; speedup vs baseline: 1.0429x; 1.0429x over previous
//
#include <hip/hip_runtime.h>
#include <math.h>

#define Hh 256
#define Ww 256
#define HW 65536
#define Bn 4
#define Cdim 60
#define Ce 120
#define NPIX (Bn*HW)

typedef const float* fp;

__device__ __forceinline__ float gelu_exact(float x){
  return 0.5f*x*(1.f + erff(x*0.70710678118654752f));
}

// decode 64-px tile id -> (b, h, tw). 1024 tiles/image (256 rows x 4 tiles).
__device__ __forceinline__ void tile_decode(int blk, int& b, int& h, int& tw){
  b = blk >> 10; int rem = blk & 1023; h = rem >> 2; tw = (rem & 3) << 6;
}

// ---------------- LFE stage 1: y1 = gelu(conv1x1(shift(src), w0, b0)) ----------------
// GEMM: M=64 px, N=120 out, K=60. W staged transposed [k][o] in TWO 60-out halves
// (stride 60, conflict-free reads) so LDS = 29.8KB -> 5 blocks/CU (was 47KB -> 3).
__global__ __launch_bounds__(256) void k_lfe1(const float* __restrict__ X, float* __restrict__ Y1,
                                              fp w0, fp b0){
  __shared__ __align__(16) float A[60*64];     // shifted input [k][p]
  __shared__ __align__(16) float Wt[60*60];    // transposed weight half [k][o_local]
  int tid = threadIdx.x;
  int b, h, tw; tile_decode(blockIdx.x, b, h, tw);
  const float* Xb = X + (size_t)b*(Cdim*HW);
  for (int idx = tid; idx < 60*64; idx += 256){
    int k = idx >> 6, p = idx & 63;
    int grp = k / 12;
    int hh = h, ww = tw + p; bool ok = true;
    if (grp == 0){ ww += 1; ok = (ww < Ww); }
    else if (grp == 1){ ww -= 1; ok = (ww >= 0); }
    else if (grp == 2){ hh = h+1; ok = (hh < Hh); }
    else if (grp == 3){ hh = h-1; ok = (hh >= 0); }
    A[idx] = ok ? Xb[k*HW + hh*Ww + ww] : 0.f;
  }
  for (int idx = tid; idx < 60*60; idx += 256){   // W half 0: outs 0..59 (coalesced read)
    int o = idx / 60, k = idx - o*60;
    Wt[k*60 + o] = w0[idx];
  }
  __syncthreads();

  int p0 = (tid & 15)*4;
  int o0 = (tid >> 4)*4;                          // 0..56 over 240 threads

  #pragma unroll 1
  for (int half = 0; half < 2; half++){
    if (tid < 240){
      float acc[4][4];
      #pragma unroll
      for (int oi = 0; oi < 4; oi++){
        float bb = b0[half*60 + o0 + oi];
        #pragma unroll
        for (int pi = 0; pi < 4; pi++) acc[oi][pi] = bb;
      }
      #pragma unroll 4
      for (int k = 0; k < 60; k++){
        float4 a4 = *(const float4*)(&A[k*64 + p0]);
        float av[4] = {a4.x,a4.y,a4.z,a4.w};
        float4 w4 = *(const float4*)(&Wt[k*60 + o0]);
        float wv[4] = {w4.x,w4.y,w4.z,w4.w};
        #pragma unroll
        for (int oi = 0; oi < 4; oi++){
          #pragma unroll
          for (int pi = 0; pi < 4; pi++)
            acc[oi][pi] += wv[oi]*av[pi];
        }
      }
      float* Yb = Y1 + (size_t)b*(Ce*HW) + h*Ww + tw + p0;
      #pragma unroll
      for (int oi = 0; oi < 4; oi++){
        int o = half*60 + o0 + oi;
        float4 r;
        r.x = gelu_exact(acc[oi][0]); r.y = gelu_exact(acc[oi][1]);
        r.z = gelu_exact(acc[oi][2]); r.w = gelu_exact(acc[oi][3]);
        *(float4*)(Yb + (size_t)o*HW) = r;
      }
    }
    if (half == 0){
      __syncthreads();                            // half-0 W reads done
      for (int idx = tid; idx < 60*60; idx += 256){  // W half 1: outs 60..119
        int o = idx / 60, k = idx - o*60;
        Wt[k*60 + o] = w0[3600 + idx];
      }
      __syncthreads();
    }
  }
}

// ---------------- LFE stage 2: X = conv1x1(shift(y1), w1, b1) + resid ----------------
// GEMM: M=64, N=60, K=120. A and W both staged per 60-k half (W half [e][c] stride 68):
// LDS = 31.7KB -> 5 blocks/CU (was 48KB -> 3).
__global__ __launch_bounds__(256) void k_lfe2(const float* __restrict__ Y1,
                                              const float* __restrict__ R,
                                              float* __restrict__ X,
                                              fp w1, fp b1){
  __shared__ __align__(16) float A[60*64];
  __shared__ __align__(16) float Wt[60*68];    // transposed weight half [e_local][c]
  int tid = threadIdx.x;
  int b, h, tw; tile_decode(blockIdx.x, b, h, tw);
  const float* Yb = Y1 + (size_t)b*(Ce*HW);
  int p0 = (tid & 15)*4;
  int o0 = (tid >> 4)*4;
  float acc[4][4];
  #pragma unroll
  for (int oi = 0; oi < 4; oi++)
    #pragma unroll
    for (int pi = 0; pi < 4; pi++) acc[oi][pi] = 0.f;

  #pragma unroll 1
  for (int half = 0; half < 2; half++){
    if (half) __syncthreads();                  // previous half's LDS reads done
    for (int idx = tid; idx < 60*64; idx += 256){
      int k = idx >> 6, p = idx & 63;
      int e = half*60 + k;
      int grp = e / 24;
      int hh = h, ww = tw + p; bool ok = true;
      if (grp == 0){ ww += 1; ok = (ww < Ww); }
      else if (grp == 1){ ww -= 1; ok = (ww >= 0); }
      else if (grp == 2){ hh = h+1; ok = (hh < Hh); }
      else if (grp == 3){ hh = h-1; ok = (hh >= 0); }
      A[idx] = ok ? Yb[e*HW + hh*Ww + ww] : 0.f;
    }
    for (int idx = tid; idx < 60*60; idx += 256){   // W half: e in [half*60, half*60+60)
      int c = idx / 60, e = idx - c*60;
      Wt[e*68 + c] = w1[c*120 + half*60 + e];
    }
    __syncthreads();
    if (tid < 240){
      #pragma unroll 4
      for (int k = 0; k < 60; k++){
        float4 a4 = *(const float4*)(&A[k*64 + p0]);
        float av[4] = {a4.x,a4.y,a4.z,a4.w};
        float4 w4 = *(const float4*)(&Wt[k*68 + o0]);
        float wv[4] = {w4.x,w4.y,w4.z,w4.w};
        #pragma unroll
        for (int oi = 0; oi < 4; oi++){
          #pragma unroll
          for (int pi = 0; pi < 4; pi++)
            acc[oi][pi] += wv[oi]*av[pi];
        }
      }
    }
  }
  if (tid < 240){
    const float* Rp = R + (size_t)b*(Cdim*HW) + h*Ww + tw + p0;
    float* Xp = X + (size_t)b*(Cdim*HW) + h*Ww + tw + p0;
    #pragma unroll
    for (int oi = 0; oi < 4; oi++){
      int o = o0 + oi;
      float bb = b1[o];
      float4 r4 = *(const float4*)(Rp + (size_t)o*HW);
      float4 out;
      out.x = acc[oi][0] + bb + r4.x;
      out.y = acc[oi][1] + bb + r4.y;
      out.z = acc[oi][2] + bb + r4.z;
      out.w = acc[oi][3] + bb + r4.w;
      *(float4*)(Xp + (size_t)o*HW) = out;
    }
  }
}

// ---------------- WSA stage 1: t = BN(conv1x1(x, pi_w, pi_b)) ----------------
// GEMM: M=64, N=60, K=60. W transposed [k][o] stride 68 with BN scale folded at staging.
__global__ __launch_bounds__(256) void k_wsat(const float* __restrict__ X, float* __restrict__ T,
                                              fp piw, fp pib, fp g, fp bt, fp m, fp v){
  __shared__ __align__(16) float A[60*64];
  __shared__ __align__(16) float Wt[60*68];
  int tid = threadIdx.x;
  int b, h, tw; tile_decode(blockIdx.x, b, h, tw);
  const float* Xb = X + (size_t)b*(Cdim*HW) + h*Ww + tw;
  for (int idx = tid; idx < 60*64; idx += 256){
    int k = idx >> 6, p = idx & 63;
    A[idx] = Xb[k*HW + p];
  }
  for (int idx = tid; idx < 60*60; idx += 256){
    int o = idx / 60, k = idx - o*60;
    float scale = g[o] * rsqrtf(v[o] + 1e-5f);
    Wt[k*68 + o] = piw[idx] * scale;
  }
  __syncthreads();
  if (tid < 240){
    int p0 = (tid & 15)*4;
    int o0 = (tid >> 4)*4;
    float acc[4][4];
    #pragma unroll
    for (int oi = 0; oi < 4; oi++)
      #pragma unroll
      for (int pi = 0; pi < 4; pi++) acc[oi][pi] = 0.f;
    #pragma unroll 4
    for (int k = 0; k < 60; k++){
      float4 a4 = *(const float4*)(&A[k*64 + p0]);
      float av[4] = {a4.x,a4.y,a4.z,a4.w};
      float4 w4 = *(const float4*)(&Wt[k*68 + o0]);
      float wv[4] = {w4.x,w4.y,w4.z,w4.w};
      #pragma unroll
      for (int oi = 0; oi < 4; oi++){
        #pragma unroll
        for (int pi = 0; pi < 4; pi++)
          acc[oi][pi] += wv[oi]*av[pi];
      }
    }
    float* Tb = T + (size_t)b*(Cdim*HW) + h*Ww + tw + p0;
    #pragma unroll
    for (int oi = 0; oi < 4; oi++){
      int o = o0 + oi;
      float scale = g[o] * rsqrtf(v[o] + 1e-5f);
      float cns   = (pib[o] - m[o])*scale + bt[o];
      float4 out;
      out.x = acc[oi][0] + cns;
      out.y = acc[oi][1] + cns;
      out.z = acc[oi][2] + cns;
      out.w = acc[oi][3] + cns;
      *(float4*)(Tb + (size_t)o*HW) = out;
    }
  }
}

// ---------------- WSA stage 2: windowed attention (parallel softmax) ----------------
// mask_w staged NATURAL [c][k] pad-61 into R2 (overwritten by scores after barrier).
__global__ __launch_bounds__(256) void k_attn(const float* __restrict__ T, float* __restrict__ Y,
                                              fp mw, fp mb){
  __shared__ __align__(16) float R1[64*68]; // sub[k*68+p], later V[tok*68+c]
  __shared__ __align__(16) float R2[64*68]; // Wn[c*61+k] (mask_w), later St[q*68+p]
  __shared__ __align__(16) float R3[60*64]; // Qt[c*64+tok]; later softmax partials scratch
  int tid = threadIdx.x;
  int blk = blockIdx.x;
  int b = blk >> 10; int ij = blk & 1023; int wi = ij >> 5; int wj = ij & 31;
  const float* Tb = T + (size_t)b*(Cdim*HW);

  for (int idx = tid; idx < Cdim*64; idx += 256){
    int k = idx >> 6, p = idx & 63;
    int u = p >> 3, vq = p & 7;
    int r  = wi*8 + 2*vq; if (r > 255) r -= 8;
    int cc = wj*8 + 2*u;  if (cc > 255) cc -= 8;
    R1[k*68 + p] = Tb[k*HW + r*Ww + cc];
  }
  for (int idx = tid; idx < Cdim*Cdim; idx += 256){   // coalesced, natural layout
    int c = idx / Cdim, k = idx - c*Cdim;
    R2[c*61 + k] = mw[idx];
  }
  __syncthreads();

  // qproj: q[p][c] = sum_k mw[c][k]*sub[k][p] + mb[c]
  if (tid < 240){
    int p0 = (tid & 15)*4, c0 = (tid >> 4)*4;
    float4 mb4 = *(const float4*)(mb + c0);
    float bias[4] = {mb4.x, mb4.y, mb4.z, mb4.w};
    float acc[4][4];
    #pragma unroll
    for (int ci = 0; ci < 4; ci++)
      #pragma unroll
      for (int pi = 0; pi < 4; pi++) acc[ci][pi] = bias[ci];
    #pragma unroll 4
    for (int k = 0; k < Cdim; k++){
      float4 a4 = *(const float4*)(&R1[k*68 + p0]);
      float av[4] = {a4.x, a4.y, a4.z, a4.w};
      #pragma unroll
      for (int ci = 0; ci < 4; ci++){
        float wv = R2[(c0+ci)*61 + k];
        #pragma unroll
        for (int pi = 0; pi < 4; pi++)
          acc[ci][pi] += wv*av[pi];
      }
    }
    #pragma unroll
    for (int ci = 0; ci < 4; ci++)
      *(float4*)(&R3[(c0+ci)*64 + p0]) = make_float4(acc[ci][0], acc[ci][1], acc[ci][2], acc[ci][3]);
  }
  __syncthreads();

  // stage V[tok][c] into R1 (sub dead); compute scores from R3
  {
    int p = tid & 63; int cg = tid >> 6;
    int pr = p >> 3, pc = p & 7;
    const float* base = Tb + (wi*8+pr)*Ww + (wj*8+pc);
    #pragma unroll
    for (int t2 = 0; t2 < 15; t2++)
      R1[p*68 + cg*15 + t2] = base[(cg*15+t2)*HW];
  }
  if (tid < 64){
    R1[tid*68 + 60] = 0.f; R1[tid*68 + 61] = 0.f;
    R1[tid*68 + 62] = 0.f; R1[tid*68 + 63] = 0.f;
  }
  {
    int p0 = (tid & 15)*4, q0 = (tid >> 4)*4;
    float acc[4][4];
    #pragma unroll
    for (int qi = 0; qi < 4; qi++)
      #pragma unroll
      for (int pi = 0; pi < 4; pi++) acc[qi][pi] = 0.f;
    #pragma unroll 4
    for (int c = 0; c < Cdim; c++){
      float4 A4 = *(const float4*)(&R3[c*64 + p0]);
      float4 B4 = *(const float4*)(&R3[c*64 + q0]);
      float Af[4] = {A4.x, A4.y, A4.z, A4.w};
      float Bf[4] = {B4.x, B4.y, B4.z, B4.w};
      #pragma unroll
      for (int qi = 0; qi < 4; qi++)
        #pragma unroll
        for (int pi = 0; pi < 4; pi++)
          acc[qi][pi] += Bf[qi]*Af[pi];
    }
    __syncthreads();   // qproj reads of R2/R3 done; V-stage R1 writes done
    #pragma unroll
    for (int qi = 0; qi < 4; qi++)
      *(float4*)(&R2[(q0+qi)*68 + p0]) = make_float4(acc[qi][0], acc[qi][1], acc[qi][2], acc[qi][3]);
  }
  __syncthreads();

  // parallel column softmax over q (all 256 threads): thread (gq,p) owns 16 q's.
  {
    int p = tid & 63, gq = tid >> 6;
    float* Sc = R3;                       // Qt dead: [0..255] max partials, [256..511] sums
    float mx = -1e30f;
    #pragma unroll
    for (int i = 0; i < 16; i++) mx = fmaxf(mx, R2[(gq*16+i)*68 + p]);
    Sc[gq*64 + p] = mx;
    __syncthreads();
    float m0 = fmaxf(fmaxf(Sc[p], Sc[64+p]), fmaxf(Sc[128+p], Sc[192+p]));
    float sum = 0.f;
    #pragma unroll
    for (int i = 0; i < 16; i++){
      int q = gq*16 + i;
      float e = __expf(R2[q*68 + p] - m0);
      R2[q*68 + p] = e; sum += e;
    }
    Sc[256 + gq*64 + p] = sum;
    __syncthreads();
    float tot = (Sc[256+p] + Sc[320+p]) + (Sc[384+p] + Sc[448+p]);
    float inv = 1.f/tot;
    #pragma unroll
    for (int i = 0; i < 16; i++) R2[(gq*16+i)*68 + p] *= inv;
  }
  __syncthreads();

  {
    int p0 = (tid & 15)*4, c0 = (tid >> 4)*4;
    float acc[4][4];
    #pragma unroll
    for (int ci = 0; ci < 4; ci++)
      #pragma unroll
      for (int pi = 0; pi < 4; pi++) acc[ci][pi] = 0.f;
    #pragma unroll 4
    for (int q = 0; q < 64; q++){
      float4 S4 = *(const float4*)(&R2[q*68 + p0]);
      float4 V4 = *(const float4*)(&R1[q*68 + c0]);
      float Sf[4] = {S4.x, S4.y, S4.z, S4.w};
      float Vf[4] = {V4.x, V4.y, V4.z, V4.w};
      #pragma unroll
      for (int ci = 0; ci < 4; ci++)
        #pragma unroll
        for (int pi = 0; pi < 4; pi++)
          acc[ci][pi] += Sf[pi]*Vf[ci];
    }
    float* Yb = Y + (size_t)b*(Cdim*HW);
    #pragma unroll
    for (int ci = 0; ci < 4; ci++){
      int c = c0 + ci;
      if (c < Cdim){
        #pragma unroll
        for (int pi = 0; pi < 4; pi++){
          int p = p0 + pi;
          Yb[c*HW + (wi*8 + (p>>3))*Ww + wj*8 + (p&7)] = acc[ci][pi];
        }
      }
    }
  }
}

// ---------------- WSA stage 3: X = conv1x1(y, po) + X ----------------
__global__ __launch_bounds__(256) void k_wsaout(const float* __restrict__ Y, float* __restrict__ X,
                                                fp pw, fp pb){
  __shared__ __align__(16) float A[60*64];
  __shared__ __align__(16) float Wt[60*68];
  int tid = threadIdx.x;
  int b, h, tw; tile_decode(blockIdx.x, b, h, tw);
  const float* Yb = Y + (size_t)b*(Cdim*HW) + h*Ww + tw;
  for (int idx = tid; idx < 60*64; idx += 256){
    int k = idx >> 6, p = idx & 63;
    A[idx] = Yb[k*HW + p];
  }
  for (int idx = tid; idx < 60*60; idx += 256){
    int o = idx / 60, k = idx - o*60;
    Wt[k*68 + o] = pw[idx];
  }
  __syncthreads();
  if (tid < 240){
    int p0 = (tid & 15)*4;
    int o0 = (tid >> 4)*4;
    float acc[4][4];
    #pragma unroll
    for (int oi = 0; oi < 4; oi++)
      #pragma unroll
      for (int pi = 0; pi < 4; pi++) acc[oi][pi] = 0.f;
    #pragma unroll 4
    for (int k = 0; k < 60; k++){
      float4 a4 = *(const float4*)(&A[k*64 + p0]);
      float av[4] = {a4.x,a4.y,a4.z,a4.w};
      float4 w4 = *(const float4*)(&Wt[k*68 + o0]);
      float wv[4] = {w4.x,w4.y,w4.z,w4.w};
      #pragma unroll
      for (int oi = 0; oi < 4; oi++){
        #pragma unroll
        for (int pi = 0; pi < 4; pi++)
          acc[oi][pi] += wv[oi]*av[pi];
      }
    }
    float* Xp = X + (size_t)b*(Cdim*HW) + h*Ww + tw + p0;
    #pragma unroll
    for (int oi = 0; oi < 4; oi++){
      int o = o0 + oi;
      float bb = pb[o];
      float4 r4 = *(const float4*)(Xp + (size_t)o*HW);
      float4 out;
      out.x = acc[oi][0] + bb + r4.x;
      out.y = acc[oi][1] + bb + r4.y;
      out.z = acc[oi][2] + bb + r4.z;
      out.w = acc[oi][3] + bb + r4.w;
      *(float4*)(Xp + (size_t)o*HW) = out;
    }
  }
}

extern "C" void kernel_launch(void* const* d_in, const int* in_sizes, int n_in,
                              void* d_out, int out_size, void* d_ws, size_t ws_size,
                              hipStream_t stream){
  fp x      = (fp)d_in[0];
  fp lfe_w0 = (fp)d_in[1];
  fp lfe_b0 = (fp)d_in[2];
  fp lfe_w1 = (fp)d_in[3];
  fp lfe_b1 = (fp)d_in[4];
  fp pi_w   = (fp)d_in[5];
  fp pi_b   = (fp)d_in[6];
  fp bn_g   = (fp)d_in[7];
  fp bn_b   = (fp)d_in[8];
  fp bn_m   = (fp)d_in[9];
  fp bn_v   = (fp)d_in[10];
  fp mask_w = (fp)d_in[11];
  fp mask_b = (fp)d_in[12];
  fp po_w   = (fp)d_in[13];
  fp po_b   = (fp)d_in[14];

  const size_t XSZ = (size_t)Bn*Cdim*HW;     // 15,728,640 floats (63 MB)
  float* X  = (float*)d_out;                 // residual stream lives in d_out (fp32)
  float* Y1 = (float*)d_ws;                  // [0, 2*XSZ): 120-ch LFE intermediate
  float* T  = Y1;                            // [0, XSZ): t-tensor (Y1 dead by then)
  float* Yw = Y1 + XSZ;                      // [XSZ, 2*XSZ): attention output

  const int NT = NPIX/64;                    // 4096 64-px tiles

  for (int d = 0; d < 2; d++){
    fp src = (d == 0) ? x : X;               // depth-0 reads the input directly
    k_lfe1  <<<NT, 256, 0, stream>>>(src, Y1, lfe_w0 + d*Ce*Cdim, lfe_b0 + d*Ce);
    k_lfe2  <<<NT, 256, 0, stream>>>(Y1, src, X, lfe_w1 + d*Ce*Cdim, lfe_b1 + d*Cdim);
    k_wsat  <<<NT, 256, 0, stream>>>(X, T, pi_w + d*Cdim*Cdim, pi_b + d*Cdim,
                                     bn_g + d*Cdim, bn_b + d*Cdim, bn_m + d*Cdim, bn_v + d*Cdim);
    k_attn  <<<Bn*32*32, 256, 0, stream>>>(T, Yw, mask_w + d*Cdim*Cdim, mask_b + d*Cdim);
    k_wsaout<<<NT, 256, 0, stream>>>(Yw, X, po_w + d*Cdim*Cdim, po_b + d*Cdim);
  }
}

// Round 8
// 890.976 us; speedup vs baseline: 1.1946x; 1.1455x over previous
//
#include <hip/hip_runtime.h>
#include <math.h>

#define Hh 256
#define Ww 256
#define HW 65536
#define Bn 4
#define Cdim 60
#define Ce 120
#define NPIX (Bn*HW)

typedef const float* fp;

// async global->LDS: wave-uniform LDS base, per-lane global addr, 4B/lane.
typedef const __attribute__((address_space(1))) void* gas_p;
typedef __attribute__((address_space(3))) void* las_p;
#define GLOAD4(SRC, DST) __builtin_amdgcn_global_load_lds((gas_p)(SRC), (las_p)(DST), 4, 0, 0)

// pin a value in a VGPR (defeats remat/sinking of the feeding load)
#define KEEP(x) asm volatile("" : "+v"(x))

__device__ __forceinline__ float gelu_exact(float x){
  return 0.5f*x*(1.f + erff(x*0.70710678118654752f));
}

// decode 64-px tile id -> (b, h, tw). 1024 tiles/image (256 rows x 4 tiles).
__device__ __forceinline__ void tile_decode(int blk, int& b, int& h, int& tw){
  b = blk >> 10; int rem = blk & 1023; h = rem >> 2; tw = (rem & 3) << 6;
}

// shifted-row async issue for LFE kernels: row e of the (possibly shifted) source
// goes to LDS row kloc. OOB lanes pre-zeroed via ds_write, gload exec-masked.
__device__ __forceinline__ void issue_shift_row(const float* __restrict__ Src, float* A,
                                                int e, int kloc, int gdiv,
                                                int h, int tw, int lane){
  int grp = e / gdiv;
  int hh = h, ww = tw + lane; bool ok = true;
  if (grp == 0){ ww += 1; ok = (ww < Ww); }
  else if (grp == 1){ ww -= 1; ok = (ww >= 0); }
  else if (grp == 2){ hh = h+1; ok = (hh < Hh); }
  else if (grp == 3){ hh = h-1; ok = (hh >= 0); }
  if (!ok) A[kloc*64 + lane] = 0.f;
  if (ok)  GLOAD4(Src + (size_t)e*HW + hh*Ww + ww, &A[kloc*64]);
}

// ---------------- LFE stage 1: y1 = gelu(conv1x1(shift(src), w0, b0)) ----------------
// Pipelined: A rows k<32 + W-half0 staged; barrier; A rows k>=32 issued ASYNC and
// drained under compute(k<32). W-half1 prefetched to regs under compute, written at
// the half boundary. LDS 29.8KB -> 5 blocks/CU.
__global__ __launch_bounds__(256) void k_lfe1(const float* __restrict__ X, float* __restrict__ Y1,
                                              fp w0, fp b0){
  __shared__ __align__(16) float A[60*64];
  __shared__ __align__(16) float Wt[60*60];    // transposed weight half [k][o_local]
  int tid = threadIdx.x;
  int lane = tid & 63, wv = tid >> 6;
  int b, h, tw; tile_decode(blockIdx.x, b, h, tw);
  const float* Xb = X + (size_t)b*(Cdim*HW);

  #pragma unroll
  for (int j = 0; j < 8; j++){                 // rows k<32
    int k = wv + j*4;
    issue_shift_row(Xb, A, k, k, 12, h, tw, lane);
  }
  for (int idx = tid; idx < 3600; idx += 256){ // W half0 (outs 0..59), transposed write
    int o = idx / 60, k = idx - o*60;
    Wt[k*60 + o] = w0[idx];
  }
  __syncthreads();                             // A(k<32) + W0 ready
  #pragma unroll
  for (int j = 8; j < 15; j++){                // rows k>=32: async, drain under compute
    int k = wv + j*4;
    issue_shift_row(Xb, A, k, k, 12, h, tw, lane);
  }
  __builtin_amdgcn_sched_barrier(0);

  int p0 = (tid & 15)*4, o0 = (tid >> 4)*4;
  float acc[4][4];
  if (tid < 240){
    #pragma unroll
    for (int oi = 0; oi < 4; oi++){
      float bb = b0[o0+oi];
      #pragma unroll
      for (int pi = 0; pi < 4; pi++) acc[oi][pi] = bb;
    }
    #pragma unroll 4
    for (int k = 0; k < 32; k++){
      float4 a4 = *(const float4*)(&A[k*64 + p0]);
      float av[4] = {a4.x,a4.y,a4.z,a4.w};
      float4 w4 = *(const float4*)(&Wt[k*60 + o0]);
      float wvv[4] = {w4.x,w4.y,w4.z,w4.w};
      #pragma unroll
      for (int oi = 0; oi < 4; oi++)
        #pragma unroll
        for (int pi = 0; pi < 4; pi++)
          acc[oi][pi] += wvv[oi]*av[pi];
    }
  }
  __syncthreads();                             // rows k>=32 landed
  float w1r[15];                               // prefetch W half1 under compute
  #pragma unroll
  for (int jj = 0; jj < 15; jj++){
    int idx = tid + jj*256;
    w1r[jj] = (idx < 3600) ? w0[3600 + idx] : 0.f;
  }
  #pragma unroll
  for (int jj = 0; jj < 15; jj++) KEEP(w1r[jj]);
  __builtin_amdgcn_sched_barrier(0);
  if (tid < 240){
    #pragma unroll 4
    for (int k = 32; k < 60; k++){
      float4 a4 = *(const float4*)(&A[k*64 + p0]);
      float av[4] = {a4.x,a4.y,a4.z,a4.w};
      float4 w4 = *(const float4*)(&Wt[k*60 + o0]);
      float wvv[4] = {w4.x,w4.y,w4.z,w4.w};
      #pragma unroll
      for (int oi = 0; oi < 4; oi++)
        #pragma unroll
        for (int pi = 0; pi < 4; pi++)
          acc[oi][pi] += wvv[oi]*av[pi];
    }
    float* Yb = Y1 + (size_t)b*(Ce*HW) + h*Ww + tw + p0;
    #pragma unroll
    for (int oi = 0; oi < 4; oi++){
      float4 r;
      r.x = gelu_exact(acc[oi][0]); r.y = gelu_exact(acc[oi][1]);
      r.z = gelu_exact(acc[oi][2]); r.w = gelu_exact(acc[oi][3]);
      *(float4*)(Yb + (size_t)(o0+oi)*HW) = r;
    }
  }
  __syncthreads();                             // all W0 reads done
  #pragma unroll
  for (int jj = 0; jj < 15; jj++){             // write W half1 from regs
    int idx = tid + jj*256;
    if (idx < 3600){ int o = idx/60, k = idx - o*60; Wt[k*60 + o] = w1r[jj]; }
  }
  __syncthreads();
  if (tid < 240){
    #pragma unroll
    for (int oi = 0; oi < 4; oi++){
      float bb = b0[60 + o0 + oi];
      #pragma unroll
      for (int pi = 0; pi < 4; pi++) acc[oi][pi] = bb;
    }
    #pragma unroll 4
    for (int k = 0; k < 60; k++){
      float4 a4 = *(const float4*)(&A[k*64 + p0]);
      float av[4] = {a4.x,a4.y,a4.z,a4.w};
      float4 w4 = *(const float4*)(&Wt[k*60 + o0]);
      float wvv[4] = {w4.x,w4.y,w4.z,w4.w};
      #pragma unroll
      for (int oi = 0; oi < 4; oi++)
        #pragma unroll
        for (int pi = 0; pi < 4; pi++)
          acc[oi][pi] += wvv[oi]*av[pi];
    }
    float* Yb = Y1 + (size_t)b*(Ce*HW) + h*Ww + tw + p0;
    #pragma unroll
    for (int oi = 0; oi < 4; oi++){
      float4 r;
      r.x = gelu_exact(acc[oi][0]); r.y = gelu_exact(acc[oi][1]);
      r.z = gelu_exact(acc[oi][2]); r.w = gelu_exact(acc[oi][3]);
      *(float4*)(Yb + (size_t)(60 + o0 + oi)*HW) = r;
    }
  }
}

// ---------------- LFE stage 2: X = conv1x1(shift(y1), w1, b1) + resid ----------------
// Per 60-e half: pipelined A staging (sub-split 32/28) as in lfe1; W-half1 prefetched
// to regs under half0's compute. LDS 31.7KB -> 5 blocks/CU.
__global__ __launch_bounds__(256) void k_lfe2(const float* __restrict__ Y1,
                                              const float* __restrict__ R,
                                              float* __restrict__ X,
                                              fp w1, fp b1){
  __shared__ __align__(16) float A[60*64];
  __shared__ __align__(16) float Wt[60*68];    // transposed weight half [e_local][c]
  int tid = threadIdx.x;
  int lane = tid & 63, wv = tid >> 6;
  int b, h, tw; tile_decode(blockIdx.x, b, h, tw);
  const float* Yb = Y1 + (size_t)b*(Ce*HW);
  int p0 = (tid & 15)*4, o0 = (tid >> 4)*4;
  float acc[4][4];
  #pragma unroll
  for (int oi = 0; oi < 4; oi++)
    #pragma unroll
    for (int pi = 0; pi < 4; pi++) acc[oi][pi] = 0.f;

  // ---- half 0 ----
  #pragma unroll
  for (int j = 0; j < 8; j++){
    int kloc = wv + j*4;
    issue_shift_row(Yb, A, kloc, kloc, 24, h, tw, lane);
  }
  for (int idx = tid; idx < 3600; idx += 256){ // W half0: e in [0,60)
    int c = idx / 60, e = idx - c*60;
    Wt[e*68 + c] = w1[c*120 + e];
  }
  __syncthreads();
  #pragma unroll
  for (int j = 8; j < 15; j++){
    int kloc = wv + j*4;
    issue_shift_row(Yb, A, kloc, kloc, 24, h, tw, lane);
  }
  __builtin_amdgcn_sched_barrier(0);
  if (tid < 240){
    #pragma unroll 4
    for (int k = 0; k < 32; k++){
      float4 a4 = *(const float4*)(&A[k*64 + p0]);
      float av[4] = {a4.x,a4.y,a4.z,a4.w};
      float4 w4 = *(const float4*)(&Wt[k*68 + o0]);
      float wvv[4] = {w4.x,w4.y,w4.z,w4.w};
      #pragma unroll
      for (int oi = 0; oi < 4; oi++)
        #pragma unroll
        for (int pi = 0; pi < 4; pi++)
          acc[oi][pi] += wvv[oi]*av[pi];
    }
  }
  __syncthreads();                             // rows >=32 landed
  float w1r[15];                               // prefetch W half1 under compute
  #pragma unroll
  for (int jj = 0; jj < 15; jj++){
    int idx = tid + jj*256;
    int c = idx / 60, e = idx - c*60;
    w1r[jj] = (idx < 3600) ? w1[c*120 + 60 + e] : 0.f;
  }
  #pragma unroll
  for (int jj = 0; jj < 15; jj++) KEEP(w1r[jj]);
  __builtin_amdgcn_sched_barrier(0);
  if (tid < 240){
    #pragma unroll 4
    for (int k = 32; k < 60; k++){
      float4 a4 = *(const float4*)(&A[k*64 + p0]);
      float av[4] = {a4.x,a4.y,a4.z,a4.w};
      float4 w4 = *(const float4*)(&Wt[k*68 + o0]);
      float wvv[4] = {w4.x,w4.y,w4.z,w4.w};
      #pragma unroll
      for (int oi = 0; oi < 4; oi++)
        #pragma unroll
        for (int pi = 0; pi < 4; pi++)
          acc[oi][pi] += wvv[oi]*av[pi];
    }
  }
  __syncthreads();                             // all half0 A/W reads done

  // ---- half 1 ----
  #pragma unroll
  for (int j = 0; j < 8; j++){
    int kloc = wv + j*4;
    issue_shift_row(Yb, A, 60 + kloc, kloc, 24, h, tw, lane);
  }
  #pragma unroll
  for (int jj = 0; jj < 15; jj++){             // write W half1 from regs
    int idx = tid + jj*256;
    if (idx < 3600){ int c = idx/60, e = idx - c*60; Wt[e*68 + c] = w1r[jj]; }
  }
  __syncthreads();
  #pragma unroll
  for (int j = 8; j < 15; j++){
    int kloc = wv + j*4;
    issue_shift_row(Yb, A, 60 + kloc, kloc, 24, h, tw, lane);
  }
  __builtin_amdgcn_sched_barrier(0);
  if (tid < 240){
    #pragma unroll 4
    for (int k = 0; k < 32; k++){
      float4 a4 = *(const float4*)(&A[k*64 + p0]);
      float av[4] = {a4.x,a4.y,a4.z,a4.w};
      float4 w4 = *(const float4*)(&Wt[k*68 + o0]);
      float wvv[4] = {w4.x,w4.y,w4.z,w4.w};
      #pragma unroll
      for (int oi = 0; oi < 4; oi++)
        #pragma unroll
        for (int pi = 0; pi < 4; pi++)
          acc[oi][pi] += wvv[oi]*av[pi];
    }
  }
  __syncthreads();
  if (tid < 240){
    #pragma unroll 4
    for (int k = 32; k < 60; k++){
      float4 a4 = *(const float4*)(&A[k*64 + p0]);
      float av[4] = {a4.x,a4.y,a4.z,a4.w};
      float4 w4 = *(const float4*)(&Wt[k*68 + o0]);
      float wvv[4] = {w4.x,w4.y,w4.z,w4.w};
      #pragma unroll
      for (int oi = 0; oi < 4; oi++)
        #pragma unroll
        for (int pi = 0; pi < 4; pi++)
          acc[oi][pi] += wvv[oi]*av[pi];
    }
    const float* Rp = R + (size_t)b*(Cdim*HW) + h*Ww + tw + p0;
    float* Xp = X + (size_t)b*(Cdim*HW) + h*Ww + tw + p0;
    #pragma unroll
    for (int oi = 0; oi < 4; oi++){
      int o = o0 + oi;
      float bb = b1[o];
      float4 r4 = *(const float4*)(Rp + (size_t)o*HW);
      float4 out;
      out.x = acc[oi][0] + bb + r4.x;
      out.y = acc[oi][1] + bb + r4.y;
      out.z = acc[oi][2] + bb + r4.z;
      out.w = acc[oi][3] + bb + r4.w;
      *(float4*)(Xp + (size_t)o*HW) = out;
    }
  }
}

// ---------------- WSA stage 1: t = BN(conv1x1(x, pi_w, pi_b)) ----------------
// Pipelined split-K staging; BN scale folded into W at staging.
__global__ __launch_bounds__(256) void k_wsat(const float* __restrict__ X, float* __restrict__ T,
                                              fp piw, fp pib, fp g, fp bt, fp m, fp v){
  __shared__ __align__(16) float A[60*64];
  __shared__ __align__(16) float Wt[60*68];
  int tid = threadIdx.x;
  int lane = tid & 63, wv = tid >> 6;
  int b, h, tw; tile_decode(blockIdx.x, b, h, tw);
  const float* Xb = X + (size_t)b*(Cdim*HW) + h*Ww + tw;

  #pragma unroll
  for (int j = 0; j < 8; j++){
    int k = wv + j*4;
    GLOAD4(Xb + (size_t)k*HW + lane, &A[k*64]);
  }
  for (int idx = tid; idx < 3600; idx += 256){
    int o = idx / 60, k = idx - o*60;
    float scale = g[o] * rsqrtf(v[o] + 1e-5f);
    Wt[k*68 + o] = piw[idx] * scale;
  }
  __syncthreads();
  #pragma unroll
  for (int j = 8; j < 15; j++){
    int k = wv + j*4;
    GLOAD4(Xb + (size_t)k*HW + lane, &A[k*64]);
  }
  __builtin_amdgcn_sched_barrier(0);

  int p0 = (tid & 15)*4, o0 = (tid >> 4)*4;
  float acc[4][4];
  if (tid < 240){
    #pragma unroll
    for (int oi = 0; oi < 4; oi++)
      #pragma unroll
      for (int pi = 0; pi < 4; pi++) acc[oi][pi] = 0.f;
    #pragma unroll 4
    for (int k = 0; k < 32; k++){
      float4 a4 = *(const float4*)(&A[k*64 + p0]);
      float av[4] = {a4.x,a4.y,a4.z,a4.w};
      float4 w4 = *(const float4*)(&Wt[k*68 + o0]);
      float wvv[4] = {w4.x,w4.y,w4.z,w4.w};
      #pragma unroll
      for (int oi = 0; oi < 4; oi++)
        #pragma unroll
        for (int pi = 0; pi < 4; pi++)
          acc[oi][pi] += wvv[oi]*av[pi];
    }
  }
  __syncthreads();
  if (tid < 240){
    #pragma unroll 4
    for (int k = 32; k < 60; k++){
      float4 a4 = *(const float4*)(&A[k*64 + p0]);
      float av[4] = {a4.x,a4.y,a4.z,a4.w};
      float4 w4 = *(const float4*)(&Wt[k*68 + o0]);
      float wvv[4] = {w4.x,w4.y,w4.z,w4.w};
      #pragma unroll
      for (int oi = 0; oi < 4; oi++)
        #pragma unroll
        for (int pi = 0; pi < 4; pi++)
          acc[oi][pi] += wvv[oi]*av[pi];
    }
    float* Tb = T + (size_t)b*(Cdim*HW) + h*Ww + tw + p0;
    #pragma unroll
    for (int oi = 0; oi < 4; oi++){
      int o = o0 + oi;
      float scale = g[o] * rsqrtf(v[o] + 1e-5f);
      float cns   = (pib[o] - m[o])*scale + bt[o];
      float4 out;
      out.x = acc[oi][0] + cns;
      out.y = acc[oi][1] + cns;
      out.z = acc[oi][2] + cns;
      out.w = acc[oi][3] + cns;
      *(float4*)(Tb + (size_t)o*HW) = out;
    }
  }
}

// ---------------- WSA stage 2: windowed attention (UNCHANGED from round 7) ----------------
__global__ __launch_bounds__(256) void k_attn(const float* __restrict__ T, float* __restrict__ Y,
                                              fp mw, fp mb){
  __shared__ __align__(16) float R1[64*68]; // sub[k*68+p], later V[tok*68+c]
  __shared__ __align__(16) float R2[64*68]; // Wn[c*61+k] (mask_w), later St[q*68+p]
  __shared__ __align__(16) float R3[60*64]; // Qt[c*64+tok]; later softmax partials scratch
  int tid = threadIdx.x;
  int blk = blockIdx.x;
  int b = blk >> 10; int ij = blk & 1023; int wi = ij >> 5; int wj = ij & 31;
  const float* Tb = T + (size_t)b*(Cdim*HW);

  for (int idx = tid; idx < Cdim*64; idx += 256){
    int k = idx >> 6, p = idx & 63;
    int u = p >> 3, vq = p & 7;
    int r  = wi*8 + 2*vq; if (r > 255) r -= 8;
    int cc = wj*8 + 2*u;  if (cc > 255) cc -= 8;
    R1[k*68 + p] = Tb[k*HW + r*Ww + cc];
  }
  for (int idx = tid; idx < Cdim*Cdim; idx += 256){
    int c = idx / Cdim, k = idx - c*Cdim;
    R2[c*61 + k] = mw[idx];
  }
  __syncthreads();

  if (tid < 240){
    int p0 = (tid & 15)*4, c0 = (tid >> 4)*4;
    float4 mb4 = *(const float4*)(mb + c0);
    float bias[4] = {mb4.x, mb4.y, mb4.z, mb4.w};
    float acc[4][4];
    #pragma unroll
    for (int ci = 0; ci < 4; ci++)
      #pragma unroll
      for (int pi = 0; pi < 4; pi++) acc[ci][pi] = bias[ci];
    #pragma unroll 4
    for (int k = 0; k < Cdim; k++){
      float4 a4 = *(const float4*)(&R1[k*68 + p0]);
      float av[4] = {a4.x, a4.y, a4.z, a4.w};
      #pragma unroll
      for (int ci = 0; ci < 4; ci++){
        float wv = R2[(c0+ci)*61 + k];
        #pragma unroll
        for (int pi = 0; pi < 4; pi++)
          acc[ci][pi] += wv*av[pi];
      }
    }
    #pragma unroll
    for (int ci = 0; ci < 4; ci++)
      *(float4*)(&R3[(c0+ci)*64 + p0]) = make_float4(acc[ci][0], acc[ci][1], acc[ci][2], acc[ci][3]);
  }
  __syncthreads();

  {
    int p = tid & 63; int cg = tid >> 6;
    int pr = p >> 3, pc = p & 7;
    const float* base = Tb + (wi*8+pr)*Ww + (wj*8+pc);
    #pragma unroll
    for (int t2 = 0; t2 < 15; t2++)
      R1[p*68 + cg*15 + t2] = base[(cg*15+t2)*HW];
  }
  if (tid < 64){
    R1[tid*68 + 60] = 0.f; R1[tid*68 + 61] = 0.f;
    R1[tid*68 + 62] = 0.f; R1[tid*68 + 63] = 0.f;
  }
  {
    int p0 = (tid & 15)*4, q0 = (tid >> 4)*4;
    float acc[4][4];
    #pragma unroll
    for (int qi = 0; qi < 4; qi++)
      #pragma unroll
      for (int pi = 0; pi < 4; pi++) acc[qi][pi] = 0.f;
    #pragma unroll 4
    for (int c = 0; c < Cdim; c++){
      float4 A4 = *(const float4*)(&R3[c*64 + p0]);
      float4 B4 = *(const float4*)(&R3[c*64 + q0]);
      float Af[4] = {A4.x, A4.y, A4.z, A4.w};
      float Bf[4] = {B4.x, B4.y, B4.z, B4.w};
      #pragma unroll
      for (int qi = 0; qi < 4; qi++)
        #pragma unroll
        for (int pi = 0; pi < 4; pi++)
          acc[qi][pi] += Bf[qi]*Af[pi];
    }
    __syncthreads();
    #pragma unroll
    for (int qi = 0; qi < 4; qi++)
      *(float4*)(&R2[(q0+qi)*68 + p0]) = make_float4(acc[qi][0], acc[qi][1], acc[qi][2], acc[qi][3]);
  }
  __syncthreads();

  {
    int p = tid & 63, gq = tid >> 6;
    float* Sc = R3;
    float mx = -1e30f;
    #pragma unroll
    for (int i = 0; i < 16; i++) mx = fmaxf(mx, R2[(gq*16+i)*68 + p]);
    Sc[gq*64 + p] = mx;
    __syncthreads();
    float m0 = fmaxf(fmaxf(Sc[p], Sc[64+p]), fmaxf(Sc[128+p], Sc[192+p]));
    float sum = 0.f;
    #pragma unroll
    for (int i = 0; i < 16; i++){
      int q = gq*16 + i;
      float e = __expf(R2[q*68 + p] - m0);
      R2[q*68 + p] = e; sum += e;
    }
    Sc[256 + gq*64 + p] = sum;
    __syncthreads();
    float tot = (Sc[256+p] + Sc[320+p]) + (Sc[384+p] + Sc[448+p]);
    float inv = 1.f/tot;
    #pragma unroll
    for (int i = 0; i < 16; i++) R2[(gq*16+i)*68 + p] *= inv;
  }
  __syncthreads();

  {
    int p0 = (tid & 15)*4, c0 = (tid >> 4)*4;
    float acc[4][4];
    #pragma unroll
    for (int ci = 0; ci < 4; ci++)
      #pragma unroll
      for (int pi = 0; pi < 4; pi++) acc[ci][pi] = 0.f;
    #pragma unroll 4
    for (int q = 0; q < 64; q++){
      float4 S4 = *(const float4*)(&R2[q*68 + p0]);
      float4 V4 = *(const float4*)(&R1[q*68 + c0]);
      float Sf[4] = {S4.x, S4.y, S4.z, S4.w};
      float Vf[4] = {V4.x, V4.y, V4.z, V4.w};
      #pragma unroll
      for (int ci = 0; ci < 4; ci++)
        #pragma unroll
        for (int pi = 0; pi < 4; pi++)
          acc[ci][pi] += Sf[pi]*Vf[ci];
    }
    float* Yb = Y + (size_t)b*(Cdim*HW);
    #pragma unroll
    for (int ci = 0; ci < 4; ci++){
      int c = c0 + ci;
      if (c < Cdim){
        #pragma unroll
        for (int pi = 0; pi < 4; pi++){
          int p = p0 + pi;
          Yb[c*HW + (wi*8 + (p>>3))*Ww + wj*8 + (p&7)] = acc[ci][pi];
        }
      }
    }
  }
}

// ---------------- WSA stage 3: X = conv1x1(y, po) + X ----------------
__global__ __launch_bounds__(256) void k_wsaout(const float* __restrict__ Y, float* __restrict__ X,
                                                fp pw, fp pb){
  __shared__ __align__(16) float A[60*64];
  __shared__ __align__(16) float Wt[60*68];
  int tid = threadIdx.x;
  int lane = tid & 63, wv = tid >> 6;
  int b, h, tw; tile_decode(blockIdx.x, b, h, tw);
  const float* Yb = Y + (size_t)b*(Cdim*HW) + h*Ww + tw;

  #pragma unroll
  for (int j = 0; j < 8; j++){
    int k = wv + j*4;
    GLOAD4(Yb + (size_t)k*HW + lane, &A[k*64]);
  }
  for (int idx = tid; idx < 3600; idx += 256){
    int o = idx / 60, k = idx - o*60;
    Wt[k*68 + o] = pw[idx];
  }
  __syncthreads();
  #pragma unroll
  for (int j = 8; j < 15; j++){
    int k = wv + j*4;
    GLOAD4(Yb + (size_t)k*HW + lane, &A[k*64]);
  }
  __builtin_amdgcn_sched_barrier(0);

  int p0 = (tid & 15)*4, o0 = (tid >> 4)*4;
  float acc[4][4];
  if (tid < 240){
    #pragma unroll
    for (int oi = 0; oi < 4; oi++)
      #pragma unroll
      for (int pi = 0; pi < 4; pi++) acc[oi][pi] = 0.f;
    #pragma unroll 4
    for (int k = 0; k < 32; k++){
      float4 a4 = *(const float4*)(&A[k*64 + p0]);
      float av[4] = {a4.x,a4.y,a4.z,a4.w};
      float4 w4 = *(const float4*)(&Wt[k*68 + o0]);
      float wvv[4] = {w4.x,w4.y,w4.z,w4.w};
      #pragma unroll
      for (int oi = 0; oi < 4; oi++)
        #pragma unroll
        for (int pi = 0; pi < 4; pi++)
          acc[oi][pi] += wvv[oi]*av[pi];
    }
  }
  __syncthreads();
  if (tid < 240){
    #pragma unroll 4
    for (int k = 32; k < 60; k++){
      float4 a4 = *(const float4*)(&A[k*64 + p0]);
      float av[4] = {a4.x,a4.y,a4.z,a4.w};
      float4 w4 = *(const float4*)(&Wt[k*68 + o0]);
      float wvv[4] = {w4.x,w4.y,w4.z,w4.w};
      #pragma unroll
      for (int oi = 0; oi < 4; oi++)
        #pragma unroll
        for (int pi = 0; pi < 4; pi++)
          acc[oi][pi] += wvv[oi]*av[pi];
    }
    float* Xp = X + (size_t)b*(Cdim*HW) + h*Ww + tw + p0;
    #pragma unroll
    for (int oi = 0; oi < 4; oi++){
      int o = o0 + oi;
      float bb = pb[o];
      float4 r4 = *(const float4*)(Xp + (size_t)o*HW);
      float4 out;
      out.x = acc[oi][0] + bb + r4.x;
      out.y = acc[oi][1] + bb + r4.y;
      out.z = acc[oi][2] + bb + r4.z;
      out.w = acc[oi][3] + bb + r4.w;
      *(float4*)(Xp + (size_t)o*HW) = out;
    }
  }
}

extern "C" void kernel_launch(void* const* d_in, const int* in_sizes, int n_in,
                              void* d_out, int out_size, void* d_ws, size_t ws_size,
                              hipStream_t stream){
  fp x      = (fp)d_in[0];
  fp lfe_w0 = (fp)d_in[1];
  fp lfe_b0 = (fp)d_in[2];
  fp lfe_w1 = (fp)d_in[3];
  fp lfe_b1 = (fp)d_in[4];
  fp pi_w   = (fp)d_in[5];
  fp pi_b   = (fp)d_in[6];
  fp bn_g   = (fp)d_in[7];
  fp bn_b   = (fp)d_in[8];
  fp bn_m   = (fp)d_in[9];
  fp bn_v   = (fp)d_in[10];
  fp mask_w = (fp)d_in[11];
  fp mask_b = (fp)d_in[12];
  fp po_w   = (fp)d_in[13];
  fp po_b   = (fp)d_in[14];

  const size_t XSZ = (size_t)Bn*Cdim*HW;     // 15,728,640 floats (63 MB)
  float* X  = (float*)d_out;                 // residual stream lives in d_out (fp32)
  float* Y1 = (float*)d_ws;                  // [0, 2*XSZ): 120-ch LFE intermediate
  float* T  = Y1;                            // [0, XSZ): t-tensor (Y1 dead by then)
  float* Yw = Y1 + XSZ;                      // [XSZ, 2*XSZ): attention output

  const int NT = NPIX/64;                    // 4096 64-px tiles

  for (int d = 0; d < 2; d++){
    fp src = (d == 0) ? x : X;               // depth-0 reads the input directly
    k_lfe1  <<<NT, 256, 0, stream>>>(src, Y1, lfe_w0 + d*Ce*Cdim, lfe_b0 + d*Ce);
    k_lfe2  <<<NT, 256, 0, stream>>>(Y1, src, X, lfe_w1 + d*Ce*Cdim, lfe_b1 + d*Cdim);
    k_wsat  <<<NT, 256, 0, stream>>>(X, T, pi_w + d*Cdim*Cdim, pi_b + d*Cdim,
                                     bn_g + d*Cdim, bn_b + d*Cdim, bn_m + d*Cdim, bn_v + d*Cdim);
    k_attn  <<<Bn*32*32, 256, 0, stream>>>(T, Yw, mask_w + d*Cdim*Cdim, mask_b + d*Cdim);
    k_wsaout<<<NT, 256, 0, stream>>>(Yw, X, po_w + d*Cdim*Cdim, po_b + d*Cdim);
  }
}